// Round 15
// baseline (791.088 us; speedup 1.0000x reference)
//
#include <hip/hip_runtime.h>

#define DD 64
#define NPW 4    // nodes per wave (gather)
#define NPB 16   // nodes per block
#define CH 4     // D chunks
#define CW 16    // halves per chunk (32 B)
#define NBD 128  // histD partial-histogram blocks
#define NBS 64   // histS partial-histogram blocks

typedef _Float16 f16x2 __attribute__((ext_vector_type(2)));
typedef _Float16 f16x8 __attribute__((ext_vector_type(8)));
typedef float f32x4 __attribute__((ext_vector_type(4)));

static __device__ __forceinline__ int rfl(int x) {
    return __builtin_amdgcn_readfirstlane(x);
}

// ---- histD: per-block LDS u8 histogram of dst + per-edge within-block rank ----
__global__ __launch_bounds__(1024) void histD_kernel(
        const int* __restrict__ dst, unsigned char* __restrict__ dstp,
        unsigned char* __restrict__ ranks, int N, int NR, int E, int slice) {
    extern __shared__ unsigned int ldsH[];
    int nw = NR >> 2;
    int t = threadIdx.x;
    for (int i = t; i < nw; i += 1024) ldsH[i] = 0u;
    __syncthreads();
    int base = blockIdx.x * slice;
    int end = min(base + slice, E);
    for (int e = base + t; e < end; e += 1024) {
        int d = __builtin_nontemporal_load(dst + e);
        unsigned int sh = (unsigned int)(d & 3) * 8u;
        unsigned int old = atomicAdd(&ldsH[d >> 2], 1u << sh);
        unsigned char r = (unsigned char)((old >> sh) & 0xFFu);
        __builtin_nontemporal_store(r, ranks + e);
    }
    __syncthreads();
    unsigned int* outp = reinterpret_cast<unsigned int*>(dstp + (size_t)blockIdx.x * NR);
    for (int i = t; i < nw; i += 1024) outp[i] = ldsH[i];
}

// ---- histS: per-block LDS u8 histogram of src ----
__global__ __launch_bounds__(1024) void histS_kernel(
        const int* __restrict__ src, unsigned char* __restrict__ srcp,
        int N, int NR, int E, int slice) {
    extern __shared__ unsigned int ldsH[];
    int nw = NR >> 2;
    int t = threadIdx.x;
    for (int i = t; i < nw; i += 1024) ldsH[i] = 0u;
    __syncthreads();
    int base = blockIdx.x * slice;
    int end = min(base + slice, E);
    for (int e = base + t; e < end; e += 1024) {
        int s = __builtin_nontemporal_load(src + e);
        atomicAdd(&ldsH[s >> 2], 1u << ((unsigned int)(s & 3) * 8u));
    }
    __syncthreads();
    unsigned int* outp = reinterpret_cast<unsigned int*>(srcp + (size_t)blockIdx.x * NR);
    for (int i = t; i < nw; i += 1024) outp[i] = ldsH[i];
}

// ---- scan1: srcp -> dis ; dstp -> per-block exclusive offsets ; node counts scan ----
__global__ __launch_bounds__(1024) void scan1_kernel(
        unsigned char* dstp, const unsigned char* __restrict__ srcp,
        float* __restrict__ dis, int* __restrict__ rowptr,
        int* __restrict__ bsum, int N, int NR) {
    __shared__ int tmp[1024];
    int t = threadIdx.x;
    int g = blockIdx.x * 1024 + t;
    int c = 0;
    if (g < N) {
        int degv = 0;
        #pragma unroll 8
        for (int i = 0; i < NBS; ++i) degv += srcp[(size_t)i * NR + g];
        dis[g] = (degv > 0) ? rsqrtf((float)degv) : 0.0f;
        #pragma unroll 8
        for (int i = 0; i < NBD; ++i) {
            size_t idx = (size_t)i * NR + g;
            int v = dstp[idx];
            dstp[idx] = (unsigned char)c;
            c += v;
        }
    }
    tmp[t] = c;
    __syncthreads();
    for (int off = 1; off < 1024; off <<= 1) {
        int a = (t >= off) ? tmp[t - off] : 0;
        __syncthreads();
        tmp[t] += a;
        __syncthreads();
    }
    if (g < N) rowptr[g] = tmp[t] - c;
    if (t == 1023) bsum[blockIdx.x] = tmp[1023];
}

__global__ __launch_bounds__(128) void scan2_kernel(int* __restrict__ data, int n) {
    __shared__ int tmp[128];
    int t = threadIdx.x;
    int v = (t < n) ? data[t] : 0;
    tmp[t] = v;
    __syncthreads();
    for (int off = 1; off < 128; off <<= 1) {
        int a = (t >= off) ? tmp[t - off] : 0;
        __syncthreads();
        tmp[t] += a;
        __syncthreads();
    }
    if (t < n) data[t] = tmp[t] - v;
}

__global__ void scan3_kernel(int* __restrict__ rowptr, const int* __restrict__ bsum,
                             int N, int E) {
    int g = blockIdx.x * blockDim.x + threadIdx.x;
    if (g < N) rowptr[g] += bsum[g >> 10];
    if (g == 0) rowptr[N] = E;
}

// ---- cvt: P0[c][node][16] = f * x[node][c*16..], f = dis>0 ? dis : 1 ----
__global__ void cvt_kernel(const float* __restrict__ x, const float* __restrict__ dis,
                           _Float16* __restrict__ p0, int N) {
    int i = blockIdx.x * blockDim.x + threadIdx.x;   // over N*8 f16x8-slots
    if (i >= N * 8) return;
    int c = i / (N * 2);
    int rem = i - c * (N * 2);
    int node = rem >> 1, g = rem & 1;
    float dv = dis[node];
    float f = (dv > 0.f) ? dv : 1.0f;
    const float4* x4 = reinterpret_cast<const float4*>(x);
    long long xi = (long long)node * 16 + c * 4 + g * 2;
    float4 a = x4[xi], b = x4[xi + 1];
    f16x8 h;
    h[0] = (_Float16)(f * a.x); h[1] = (_Float16)(f * a.y);
    h[2] = (_Float16)(f * a.z); h[3] = (_Float16)(f * a.w);
    h[4] = (_Float16)(f * b.x); h[5] = (_Float16)(f * b.y);
    h[6] = (_Float16)(f * b.z); h[7] = (_Float16)(f * b.w);
    *reinterpret_cast<f16x8*>(p0 + (size_t)c * N * CW + (size_t)node * CW + g * 8) = h;
}

// ---- CSR fill (no atomics, src-only 4B adjacency) ----
__global__ void fill_kernel(const int* __restrict__ src, const int* __restrict__ dst,
                            const int* __restrict__ rowptr,
                            const unsigned char* __restrict__ dstp,
                            const unsigned char* __restrict__ ranks,
                            int* __restrict__ adjS, int E, int slice, int NR) {
    int e = blockIdx.x * blockDim.x + threadIdx.x;
    if (e < E) {
        int s = __builtin_nontemporal_load(src + e);
        int d = __builtin_nontemporal_load(dst + e);
        int i = e / slice;
        int rank = __builtin_nontemporal_load(ranks + e);
        int pos = rowptr[d] + (int)dstp[(size_t)i * NR + d] + rank;
        adjS[pos] = s;
    }
}

// ---- prop_chunk: Pout[c] = scale*dis^2*gathersum(Pin[c]) - Pt0[c] ----
// One 3.2MB chunk table per dispatch -> L2-resident. 8 slots x 8 qlanes x f16x2.
// adj/t0/out are NT (don't evict the table).
__global__ __launch_bounds__(256, 8) void prop_chunk_kernel(
        const int* __restrict__ rowptr, const int* __restrict__ adjS,
        const float* __restrict__ dis,
        const _Float16* __restrict__ Pin, const _Float16* Pt0,
        _Float16* __restrict__ Pout, float scale, int chunk, int N) {
    int t = threadIdx.x;
    int nl = t >> 6, lane = t & 63;
    int s = lane >> 3, q = lane & 7;
    int node0 = blockIdx.x * NPB + nl * NPW;
    const _Float16* hC = Pin + (size_t)chunk * N * CW;
    const _Float16* t0C = Pt0 ? Pt0 + (size_t)chunk * N * CW : (const _Float16*)0;
    _Float16* oC = Pout + (size_t)chunk * N * CW;

    for (int ni = 0; ni < NPW; ++ni) {
        int node = node0 + ni;
        if (node >= N) return;
        int beg = rfl(rowptr[node]);
        int end = rfl(rowptr[node + 1]);
        float a0 = 0.f, a1 = 0.f;
        int j = beg + s;
        int e0 = (j < end) ? __builtin_nontemporal_load(adjS + j) : 0;
        int e1 = (j + 8 < end) ? __builtin_nontemporal_load(adjS + j + 8) : 0;
        float m0 = (j < end) ? 1.f : 0.f;
        float m1 = (j + 8 < end) ? 1.f : 0.f;
        while (j < end) {
            int jn = j + 16;
            int n0 = (jn < end) ? __builtin_nontemporal_load(adjS + jn) : 0;
            int n1 = (jn + 8 < end) ? __builtin_nontemporal_load(adjS + jn + 8) : 0;
            float nm0 = (jn < end) ? 1.f : 0.f;
            float nm1 = (jn + 8 < end) ? 1.f : 0.f;
            f16x2 g0 = *reinterpret_cast<const f16x2*>(hC + (size_t)e0 * CW + q * 2);
            f16x2 g1 = *reinterpret_cast<const f16x2*>(hC + (size_t)e1 * CW + q * 2);
            a0 += m0 * (float)g0[0] + m1 * (float)g1[0];
            a1 += m0 * (float)g0[1] + m1 * (float)g1[1];
            e0 = n0; e1 = n1; m0 = nm0; m1 = nm1; j = jn;
        }
        #pragma unroll
        for (int m = 8; m < 64; m <<= 1) {
            a0 += __shfl_xor(a0, m, 64);
            a1 += __shfl_xor(a1, m, 64);
        }
        if (s == 0) {
            float dv = dis[node];
            float cf = scale * dv * dv;
            size_t base = (size_t)node * CW + q * 2;
            float v0 = cf * a0, v1 = cf * a1;
            if (t0C) {
                f16x2 t0v = __builtin_nontemporal_load(
                    reinterpret_cast<const f16x2*>(t0C + base));
                v0 -= (float)t0v[0];
                v1 -= (float)t0v[1];
            }
            f16x2 vh;
            vh[0] = (_Float16)v0;
            vh[1] = (_Float16)v1;
            __builtin_nontemporal_store(vh, reinterpret_cast<f16x2*>(oC + base));
        }
    }
}

// ---- A-frag direct load from chunked P: row=node lr, k = kt*32 + lk*8 + i ----
static __device__ __forceinline__ f16x8 afrag(const _Float16* __restrict__ P,
                                              int N, int node, int kt, int lk) {
    int c = kt * 2 + (lk >> 1);
    int off = (lk & 1) * 8;
    return *reinterpret_cast<const f16x8*>(P + (size_t)c * N * CW +
                                           (size_t)node * CW + off);
}

// ---- gemm2: out = b + invd*(P0@W0 + P1@W1)   [invd factors out per row] ----
__global__ __launch_bounds__(256, 8) void gemm2_kernel(
        const _Float16* __restrict__ P0, const _Float16* __restrict__ P1,
        const float* __restrict__ dis,
        const float* __restrict__ W0, const float* __restrict__ W1,
        const float* __restrict__ bias, float* __restrict__ out, int N) {
    int t = threadIdx.x;
    int nl = t >> 6, lane = t & 63;
    int ct = nl, lr = lane & 15, lk = lane >> 4;
    f16x8 bf0[2], bf1[2];
    #pragma unroll
    for (int kt = 0; kt < 2; ++kt)
        #pragma unroll
        for (int i = 0; i < 8; ++i) {
            int r = kt * 32 + lk * 8 + i;
            bf0[kt][i] = (_Float16)W0[r * DD + ct * 16 + lr];
            bf1[kt][i] = (_Float16)W1[r * DD + ct * 16 + lr];
        }
    int nb0 = blockIdx.x * NPB;
    int node = min(nb0 + lr, N - 1);
    f32x4 d = {0.f, 0.f, 0.f, 0.f};
    #pragma unroll
    for (int kt = 0; kt < 2; ++kt) {
        d = __builtin_amdgcn_mfma_f32_16x16x32_f16(afrag(P0, N, node, kt, lk),
                                                   bf0[kt], d, 0, 0, 0);
        d = __builtin_amdgcn_mfma_f32_16x16x32_f16(afrag(P1, N, node, kt, lk),
                                                   bf1[kt], d, 0, 0, 0);
    }
    int nvb = min(NPB, N - nb0);
    int col = ct * 16 + lr;
    float bv = bias[col];
    #pragma unroll
    for (int r = 0; r < 4; ++r) {
        int row = lk * 4 + r;
        if (row < nvb) {
            float dv = dis[nb0 + row];
            float invd = (dv > 0.f) ? 1.f / dv : 1.f;
            long long o = (long long)(nb0 + row) * DD + col;
            out[o] = bv + invd * d[r];
        }
    }
}

// ---- gemm3: out += invd*(P2@W2 + P3@W3 + P4@W4) ----
__global__ __launch_bounds__(256, 8) void gemm3_kernel(
        const _Float16* __restrict__ P2, const _Float16* __restrict__ P3,
        const _Float16* __restrict__ P4, const float* __restrict__ dis,
        const float* __restrict__ W2, const float* __restrict__ W3,
        const float* __restrict__ W4, float* __restrict__ out, int N) {
    int t = threadIdx.x;
    int nl = t >> 6, lane = t & 63;
    int ct = nl, lr = lane & 15, lk = lane >> 4;
    f16x8 bf2[2], bf3[2], bf4[2];
    #pragma unroll
    for (int kt = 0; kt < 2; ++kt)
        #pragma unroll
        for (int i = 0; i < 8; ++i) {
            int r = kt * 32 + lk * 8 + i;
            bf2[kt][i] = (_Float16)W2[r * DD + ct * 16 + lr];
            bf3[kt][i] = (_Float16)W3[r * DD + ct * 16 + lr];
            bf4[kt][i] = (_Float16)W4[r * DD + ct * 16 + lr];
        }
    int nb0 = blockIdx.x * NPB;
    int node = min(nb0 + lr, N - 1);
    f32x4 d = {0.f, 0.f, 0.f, 0.f};
    #pragma unroll
    for (int kt = 0; kt < 2; ++kt) {
        d = __builtin_amdgcn_mfma_f32_16x16x32_f16(afrag(P2, N, node, kt, lk),
                                                   bf2[kt], d, 0, 0, 0);
        d = __builtin_amdgcn_mfma_f32_16x16x32_f16(afrag(P3, N, node, kt, lk),
                                                   bf3[kt], d, 0, 0, 0);
        d = __builtin_amdgcn_mfma_f32_16x16x32_f16(afrag(P4, N, node, kt, lk),
                                                   bf4[kt], d, 0, 0, 0);
    }
    int nvb = min(NPB, N - nb0);
    int col = ct * 16 + lr;
    #pragma unroll
    for (int r = 0; r < 4; ++r) {
        int row = lk * 4 + r;
        if (row < nvb) {
            float dv = dis[nb0 + row];
            float invd = (dv > 0.f) ? 1.f / dv : 1.f;
            long long o = (long long)(nb0 + row) * DD + col;
            out[o] = out[o] + invd * d[r];
        }
    }
}

// ---- gemm1 (generic-K fallback): out += invd*(P@Wk) ----
__global__ __launch_bounds__(256, 8) void gemm1_kernel(
        const _Float16* __restrict__ P, const float* __restrict__ dis,
        const float* __restrict__ Wk, float* __restrict__ out, int N) {
    int t = threadIdx.x;
    int nl = t >> 6, lane = t & 63;
    int ct = nl, lr = lane & 15, lk = lane >> 4;
    f16x8 bf[2];
    #pragma unroll
    for (int kt = 0; kt < 2; ++kt)
        #pragma unroll
        for (int i = 0; i < 8; ++i) {
            int r = kt * 32 + lk * 8 + i;
            bf[kt][i] = (_Float16)Wk[r * DD + ct * 16 + lr];
        }
    int nb0 = blockIdx.x * NPB;
    int node = min(nb0 + lr, N - 1);
    f32x4 d = {0.f, 0.f, 0.f, 0.f};
    #pragma unroll
    for (int kt = 0; kt < 2; ++kt)
        d = __builtin_amdgcn_mfma_f32_16x16x32_f16(afrag(P, N, node, kt, lk),
                                                   bf[kt], d, 0, 0, 0);
    int nvb = min(NPB, N - nb0);
    int col = ct * 16 + lr;
    #pragma unroll
    for (int r = 0; r < 4; ++r) {
        int row = lk * 4 + r;
        if (row < nvb) {
            float dv = dis[nb0 + row];
            float invd = (dv > 0.f) ? 1.f / dv : 1.f;
            long long o = (long long)(nb0 + row) * DD + col;
            out[o] = out[o] + invd * d[r];
        }
    }
}

extern "C" void kernel_launch(void* const* d_in, const int* in_sizes, int n_in,
                              void* d_out, int out_size, void* d_ws, size_t ws_size,
                              hipStream_t stream) {
    const float* x  = (const float*)d_in[0];
    const int*   ei = (const int*)d_in[1];
    const float* W  = (const float*)d_in[2];
    const float* b  = (const float*)d_in[3];
    float* out = (float*)d_out;

    const int N = in_sizes[0] / DD;
    const int E = in_sizes[1] / 2;
    const int K = in_sizes[2] / (DD * DD);
    const long long ND = (long long)N * DD;
    const int NR = ((N + 3) / 4) * 4;

    const int* src = ei;
    const int* dst = ei + E;

    size_t off = 0;
    char* base = (char*)d_ws;
    auto alloc = [&](size_t bytes) {
        char* p = base + off;
        off = (off + bytes + 63) & ~(size_t)63;
        return p;
    };
    float* dis = (float*)alloc((size_t)N * 4);
    int* rowptr = (int*)alloc((size_t)(N + 1) * 4);
    int* bsum = (int*)alloc(512);
    unsigned char* dstp = (unsigned char*)alloc((size_t)NBD * NR);
    unsigned char* srcp = (unsigned char*)alloc((size_t)NBS * NR);
    unsigned char* ranks = (unsigned char*)alloc((size_t)E);
    int* adjS = (int*)alloc((size_t)E * 4);
    _Float16* bufA = (_Float16*)alloc((size_t)ND * 2);
    _Float16* bufB = (_Float16*)alloc((size_t)ND * 2);
    _Float16* bufC = (_Float16*)alloc((size_t)ND * 2);

    const int sliceD = (E + NBD - 1) / NBD;
    const int sliceS = (E + NBS - 1) / NBS;
    const size_t ldsH = (size_t)NR;

    histD_kernel<<<NBD, 1024, ldsH, stream>>>(dst, dstp, ranks, N, NR, E, sliceD);
    histS_kernel<<<NBS, 1024, ldsH, stream>>>(src, srcp, N, NR, E, sliceS);

    const int nb = (N + 1023) / 1024;
    scan1_kernel<<<nb, 1024, 0, stream>>>(dstp, srcp, dis, rowptr, bsum, N, NR);
    scan2_kernel<<<1, 128, 0, stream>>>(bsum, nb);
    scan3_kernel<<<(N + 255) / 256, 256, 0, stream>>>(rowptr, bsum, N, E);

    cvt_kernel<<<(N * 8 + 255) / 256, 256, 0, stream>>>(x, dis, bufA, N);

    fill_kernel<<<(E + 255) / 256, 256, 0, stream>>>(src, dst, rowptr, dstp,
                                                     ranks, adjS, E, sliceD, NR);

    const int pgrid = (N + NPB - 1) / NPB;
    const int Wsz = DD * DD;

    // P1 = -dis^2 * gathersum(P0): 4 chunk dispatches (table L2-resident each)
    for (int c = 0; c < CH; ++c)
        prop_chunk_kernel<<<pgrid, 256, 0, stream>>>(rowptr, adjS, dis, bufA,
                                                     (const _Float16*)0, bufB,
                                                     -1.0f, c, N);
    // out = b + invd*(P0@W0 + P1@W1)
    gemm2_kernel<<<pgrid, 256, 0, stream>>>(bufA, bufB, dis, W, W + Wsz, b, out, N);

    if (K == 5) {
        // P2 = -2 dis^2 gather(P1) - P0 -> bufC
        for (int c = 0; c < CH; ++c)
            prop_chunk_kernel<<<pgrid, 256, 0, stream>>>(rowptr, adjS, dis, bufB,
                                                         bufA, bufC, -2.0f, c, N);
        // P3 -> bufA (P0 dead after gemm2)
        for (int c = 0; c < CH; ++c)
            prop_chunk_kernel<<<pgrid, 256, 0, stream>>>(rowptr, adjS, dis, bufC,
                                                         bufB, bufA, -2.0f, c, N);
        // P4 -> bufB (P1 dead)
        for (int c = 0; c < CH; ++c)
            prop_chunk_kernel<<<pgrid, 256, 0, stream>>>(rowptr, adjS, dis, bufA,
                                                         bufC, bufB, -2.0f, c, N);
        // out += invd*(P2@W2 + P3@W3 + P4@W4)
        gemm3_kernel<<<pgrid, 256, 0, stream>>>(bufC, bufA, bufB, dis,
                                                W + 2 * Wsz, W + 3 * Wsz, W + 4 * Wsz,
                                                out, N);
    } else {
        // generic: 3-buffer rotation + per-k accumulate GEMM
        _Float16* t0 = bufA;
        _Float16* h  = bufB;
        _Float16* fr = bufC;
        for (int k = 2; k < K; ++k) {
            for (int c = 0; c < CH; ++c)
                prop_chunk_kernel<<<pgrid, 256, 0, stream>>>(rowptr, adjS, dis, h,
                                                             t0, fr, -2.0f, c, N);
            gemm1_kernel<<<pgrid, 256, 0, stream>>>(fr, dis, W + (long long)k * Wsz,
                                                    out, N);
            _Float16* nfree = t0;
            t0 = h; h = fr; fr = nfree;
        }
    }
}

// Round 16
// 370.577 us; speedup vs baseline: 2.1347x; 2.1347x over previous
//
#include <hip/hip_runtime.h>

#define DD 64
#define NPB 16   // nodes per block (4 waves x 4 concurrent nodes)
#define NBD 128  // histD partial-histogram blocks
#define NBS 64   // histS partial-histogram blocks

typedef _Float16 f16x8 __attribute__((ext_vector_type(8)));
typedef float f32x4 __attribute__((ext_vector_type(4)));

// ---- histD: per-block LDS u8 histogram of dst + per-edge within-block rank ----
__global__ __launch_bounds__(1024) void histD_kernel(
        const int* __restrict__ dst, unsigned char* __restrict__ dstp,
        unsigned char* __restrict__ ranks, int N, int NR, int E, int slice) {
    extern __shared__ unsigned int ldsH[];
    int nw = NR >> 2;
    int t = threadIdx.x;
    for (int i = t; i < nw; i += 1024) ldsH[i] = 0u;
    __syncthreads();
    int base = blockIdx.x * slice;
    int end = min(base + slice, E);
    for (int e = base + t; e < end; e += 1024) {
        int d = __builtin_nontemporal_load(dst + e);
        unsigned int sh = (unsigned int)(d & 3) * 8u;
        unsigned int old = atomicAdd(&ldsH[d >> 2], 1u << sh);
        unsigned char r = (unsigned char)((old >> sh) & 0xFFu);
        __builtin_nontemporal_store(r, ranks + e);
    }
    __syncthreads();
    unsigned int* outp = reinterpret_cast<unsigned int*>(dstp + (size_t)blockIdx.x * NR);
    for (int i = t; i < nw; i += 1024) outp[i] = ldsH[i];
}

// ---- histS: per-block LDS u8 histogram of src ----
__global__ __launch_bounds__(1024) void histS_kernel(
        const int* __restrict__ src, unsigned char* __restrict__ srcp,
        int N, int NR, int E, int slice) {
    extern __shared__ unsigned int ldsH[];
    int nw = NR >> 2;
    int t = threadIdx.x;
    for (int i = t; i < nw; i += 1024) ldsH[i] = 0u;
    __syncthreads();
    int base = blockIdx.x * slice;
    int end = min(base + slice, E);
    for (int e = base + t; e < end; e += 1024) {
        int s = __builtin_nontemporal_load(src + e);
        atomicAdd(&ldsH[s >> 2], 1u << ((unsigned int)(s & 3) * 8u));
    }
    __syncthreads();
    unsigned int* outp = reinterpret_cast<unsigned int*>(srcp + (size_t)blockIdx.x * NR);
    for (int i = t; i < nw; i += 1024) outp[i] = ldsH[i];
}

// ---- scan1: srcp -> dis ; dstp -> per-block exclusive offsets ; node counts scan ----
__global__ __launch_bounds__(1024) void scan1_kernel(
        unsigned char* dstp, const unsigned char* __restrict__ srcp,
        float* __restrict__ dis, int* __restrict__ rowptr,
        int* __restrict__ bsum, int N, int NR) {
    __shared__ int tmp[1024];
    int t = threadIdx.x;
    int g = blockIdx.x * 1024 + t;
    int c = 0;
    if (g < N) {
        int degv = 0;
        #pragma unroll 8
        for (int i = 0; i < NBS; ++i) degv += srcp[(size_t)i * NR + g];
        dis[g] = (degv > 0) ? rsqrtf((float)degv) : 0.0f;
        #pragma unroll 8
        for (int i = 0; i < NBD; ++i) {
            size_t idx = (size_t)i * NR + g;
            int v = dstp[idx];
            dstp[idx] = (unsigned char)c;
            c += v;
        }
    }
    tmp[t] = c;
    __syncthreads();
    for (int off = 1; off < 1024; off <<= 1) {
        int a = (t >= off) ? tmp[t - off] : 0;
        __syncthreads();
        tmp[t] += a;
        __syncthreads();
    }
    if (g < N) rowptr[g] = tmp[t] - c;
    if (t == 1023) bsum[blockIdx.x] = tmp[1023];
}

__global__ __launch_bounds__(128) void scan2_kernel(int* __restrict__ data, int n) {
    __shared__ int tmp[128];
    int t = threadIdx.x;
    int v = (t < n) ? data[t] : 0;
    tmp[t] = v;
    __syncthreads();
    for (int off = 1; off < 128; off <<= 1) {
        int a = (t >= off) ? tmp[t - off] : 0;
        __syncthreads();
        tmp[t] += a;
        __syncthreads();
    }
    if (t < n) data[t] = tmp[t] - v;
}

__global__ void scan3_kernel(int* __restrict__ rowptr, const int* __restrict__ bsum,
                             int N, int E) {
    int g = blockIdx.x * blockDim.x + threadIdx.x;
    if (g < N) rowptr[g] += bsum[g >> 10];
    if (g == 0) rowptr[N] = E;
}

// ---- cvt: P0[node][64] = f * x[node][:], f = dis>0 ? dis : 1 (fp16) ----
__global__ void cvt_kernel(const float* __restrict__ x, const float* __restrict__ dis,
                           _Float16* __restrict__ p0, long long n8) {
    long long i = (long long)blockIdx.x * blockDim.x + threadIdx.x;
    if (i < n8) {
        int node = (int)(i >> 3);
        float dv = dis[node];
        float f = (dv > 0.f) ? dv : 1.0f;
        const float4* x4 = reinterpret_cast<const float4*>(x);
        float4 a = x4[i * 2], b = x4[i * 2 + 1];
        f16x8 h;
        h[0] = (_Float16)(f * a.x); h[1] = (_Float16)(f * a.y);
        h[2] = (_Float16)(f * a.z); h[3] = (_Float16)(f * a.w);
        h[4] = (_Float16)(f * b.x); h[5] = (_Float16)(f * b.y);
        h[6] = (_Float16)(f * b.z); h[7] = (_Float16)(f * b.w);
        reinterpret_cast<f16x8*>(p0)[i] = h;
    }
}

// ---- CSR fill (no atomics, src-only 4B adjacency) ----
__global__ void fill_kernel(const int* __restrict__ src, const int* __restrict__ dst,
                            const int* __restrict__ rowptr,
                            const unsigned char* __restrict__ dstp,
                            const unsigned char* __restrict__ ranks,
                            int* __restrict__ adjS, int E, int slice, int NR) {
    int e = blockIdx.x * blockDim.x + threadIdx.x;
    if (e < E) {
        int s = __builtin_nontemporal_load(src + e);
        int d = __builtin_nontemporal_load(dst + e);
        int i = e / slice;
        int rank = __builtin_nontemporal_load(ranks + e);
        int pos = rowptr[d] + (int)dstp[(size_t)i * NR + d] + rank;
        adjS[pos] = s;
    }
}

// ---- prop: Pout = scale*dis^2*gathersum(Pin) - Pt0 ----
// 4 concurrent nodes per wave: lane = (ng<<4)|(s<<3)|q. Per (node,slot) group:
// 4-deep row pipeline with adj prefetch -> up to 32 rows in flight per wave.
// Single shfl-xor(8) reduce. t0/pout NT (single-use streams).
__global__ __launch_bounds__(256, 8) void prop_kernel(
        const int* __restrict__ rowptr, const int* __restrict__ adjS,
        const float* __restrict__ dis,
        const _Float16* __restrict__ h, const _Float16* t0,
        _Float16* __restrict__ pout, float scale, int N) {
    int t = threadIdx.x;
    int nl = t >> 6, lane = t & 63;
    int q = lane & 7;            // column chunk (8 halves)
    int s = (lane >> 3) & 1;     // edge parity slot
    int ng = lane >> 4;          // node sub-index 0..3
    int node = blockIdx.x * NPB + nl * 4 + ng;
    bool valid = node < N;
    const f16x8* h8 = reinterpret_cast<const f16x8*>(h);

    int beg = 0, end = 0;
    if (valid) { beg = rowptr[node]; end = rowptr[node + 1]; }

    float acc[8];
    #pragma unroll
    for (int i = 0; i < 8; ++i) acc[i] = 0.f;

    int j = beg + s;
    int e0 = (j < end) ? adjS[j] : 0;
    int e1 = (j + 2 < end) ? adjS[j + 2] : 0;
    int e2 = (j + 4 < end) ? adjS[j + 4] : 0;
    int e3 = (j + 6 < end) ? adjS[j + 6] : 0;
    float m0 = (j < end) ? 1.f : 0.f;
    float m1 = (j + 2 < end) ? 1.f : 0.f;
    float m2 = (j + 4 < end) ? 1.f : 0.f;
    float m3 = (j + 6 < end) ? 1.f : 0.f;
    while (j < end) {
        int jn = j + 8;
        int n0 = (jn < end) ? adjS[jn] : 0;
        int n1 = (jn + 2 < end) ? adjS[jn + 2] : 0;
        int n2 = (jn + 4 < end) ? adjS[jn + 4] : 0;
        int n3 = (jn + 6 < end) ? adjS[jn + 6] : 0;
        float nm0 = (jn < end) ? 1.f : 0.f;
        float nm1 = (jn + 2 < end) ? 1.f : 0.f;
        float nm2 = (jn + 4 < end) ? 1.f : 0.f;
        float nm3 = (jn + 6 < end) ? 1.f : 0.f;
        f16x8 g0 = h8[(size_t)e0 * 8 + q];
        f16x8 g1 = h8[(size_t)e1 * 8 + q];
        f16x8 g2 = h8[(size_t)e2 * 8 + q];
        f16x8 g3 = h8[(size_t)e3 * 8 + q];
        #pragma unroll
        for (int i = 0; i < 8; ++i) {
            acc[i] += m0 * (float)g0[i] + m1 * (float)g1[i];
            acc[i] += m2 * (float)g2[i] + m3 * (float)g3[i];
        }
        e0 = n0; e1 = n1; e2 = n2; e3 = n3;
        m0 = nm0; m1 = nm1; m2 = nm2; m3 = nm3;
        j = jn;
    }
    #pragma unroll
    for (int i = 0; i < 8; ++i) acc[i] += __shfl_xor(acc[i], 8, 64);

    if (s == 0 && valid) {
        float dv = dis[node];
        float cf = scale * dv * dv;
        size_t base = (size_t)node * DD + q * 8;
        f16x8 vh;
        if (t0) {
            f16x8 t0v = __builtin_nontemporal_load(
                reinterpret_cast<const f16x8*>(t0 + base));
            #pragma unroll
            for (int i = 0; i < 8; ++i)
                vh[i] = (_Float16)(cf * acc[i] - (float)t0v[i]);
        } else {
            #pragma unroll
            for (int i = 0; i < 8; ++i) vh[i] = (_Float16)(cf * acc[i]);
        }
        __builtin_nontemporal_store(vh, reinterpret_cast<f16x8*>(pout + base));
    }
}

// ---- A-frag: row = node, k = kt*32 + lk*8 + i (contiguous 16B) ----
static __device__ __forceinline__ f16x8 afrag(const _Float16* __restrict__ P,
                                              int node, int kt, int lk) {
    return *reinterpret_cast<const f16x8*>(P + (size_t)node * DD + kt * 32 + lk * 8);
}

// ---- gemm5: out = b + invd*(P0@W0+..+P4@W4)  (write-only out) ----
__global__ __launch_bounds__(256, 4) void gemm5_kernel(
        const _Float16* __restrict__ P0, const _Float16* __restrict__ P1,
        const _Float16* __restrict__ P2, const _Float16* __restrict__ P3,
        const _Float16* __restrict__ P4,
        const float* __restrict__ dis, const float* __restrict__ W,
        const float* __restrict__ bias, float* __restrict__ out, int N) {
    int t = threadIdx.x;
    int nl = t >> 6, lane = t & 63;
    int ct = nl, lr = lane & 15, lk = lane >> 4;
    f16x8 bf[5][2];
    #pragma unroll
    for (int k = 0; k < 5; ++k)
        #pragma unroll
        for (int kt = 0; kt < 2; ++kt)
            #pragma unroll
            for (int i = 0; i < 8; ++i) {
                int r = kt * 32 + lk * 8 + i;
                bf[k][kt][i] = (_Float16)W[(size_t)k * DD * DD + r * DD + ct * 16 + lr];
            }
    int nb0 = blockIdx.x * NPB;
    int node = min(nb0 + lr, N - 1);
    f32x4 d = {0.f, 0.f, 0.f, 0.f};
    #pragma unroll
    for (int kt = 0; kt < 2; ++kt) {
        d = __builtin_amdgcn_mfma_f32_16x16x32_f16(afrag(P0, node, kt, lk), bf[0][kt], d, 0, 0, 0);
        d = __builtin_amdgcn_mfma_f32_16x16x32_f16(afrag(P1, node, kt, lk), bf[1][kt], d, 0, 0, 0);
        d = __builtin_amdgcn_mfma_f32_16x16x32_f16(afrag(P2, node, kt, lk), bf[2][kt], d, 0, 0, 0);
        d = __builtin_amdgcn_mfma_f32_16x16x32_f16(afrag(P3, node, kt, lk), bf[3][kt], d, 0, 0, 0);
        d = __builtin_amdgcn_mfma_f32_16x16x32_f16(afrag(P4, node, kt, lk), bf[4][kt], d, 0, 0, 0);
    }
    int nvb = min(NPB, N - nb0);
    int col = ct * 16 + lr;
    float bv = bias[col];
    #pragma unroll
    for (int r = 0; r < 4; ++r) {
        int row = lk * 4 + r;
        if (row < nvb) {
            float dv = dis[nb0 + row];
            float invd = (dv > 0.f) ? 1.f / dv : 1.f;
            long long o = (long long)(nb0 + row) * DD + col;
            out[o] = bv + invd * d[r];
        }
    }
}

// ---- gemm2 (fallback): out = b + invd*(P0@W0 + P1@W1) ----
__global__ __launch_bounds__(256, 8) void gemm2_kernel(
        const _Float16* __restrict__ P0, const _Float16* __restrict__ P1,
        const float* __restrict__ dis,
        const float* __restrict__ W0, const float* __restrict__ W1,
        const float* __restrict__ bias, float* __restrict__ out, int N) {
    int t = threadIdx.x;
    int nl = t >> 6, lane = t & 63;
    int ct = nl, lr = lane & 15, lk = lane >> 4;
    f16x8 bf0[2], bf1[2];
    #pragma unroll
    for (int kt = 0; kt < 2; ++kt)
        #pragma unroll
        for (int i = 0; i < 8; ++i) {
            int r = kt * 32 + lk * 8 + i;
            bf0[kt][i] = (_Float16)W0[r * DD + ct * 16 + lr];
            bf1[kt][i] = (_Float16)W1[r * DD + ct * 16 + lr];
        }
    int nb0 = blockIdx.x * NPB;
    int node = min(nb0 + lr, N - 1);
    f32x4 d = {0.f, 0.f, 0.f, 0.f};
    #pragma unroll
    for (int kt = 0; kt < 2; ++kt) {
        d = __builtin_amdgcn_mfma_f32_16x16x32_f16(afrag(P0, node, kt, lk), bf0[kt], d, 0, 0, 0);
        d = __builtin_amdgcn_mfma_f32_16x16x32_f16(afrag(P1, node, kt, lk), bf1[kt], d, 0, 0, 0);
    }
    int nvb = min(NPB, N - nb0);
    int col = ct * 16 + lr;
    float bv = bias[col];
    #pragma unroll
    for (int r = 0; r < 4; ++r) {
        int row = lk * 4 + r;
        if (row < nvb) {
            float dv = dis[nb0 + row];
            float invd = (dv > 0.f) ? 1.f / dv : 1.f;
            long long o = (long long)(nb0 + row) * DD + col;
            out[o] = bv + invd * d[r];
        }
    }
}

// ---- gemm1 (fallback): out += invd*(P@Wk) ----
__global__ __launch_bounds__(256, 8) void gemm1_kernel(
        const _Float16* __restrict__ P, const float* __restrict__ dis,
        const float* __restrict__ Wk, float* __restrict__ out, int N) {
    int t = threadIdx.x;
    int nl = t >> 6, lane = t & 63;
    int ct = nl, lr = lane & 15, lk = lane >> 4;
    f16x8 bf[2];
    #pragma unroll
    for (int kt = 0; kt < 2; ++kt)
        #pragma unroll
        for (int i = 0; i < 8; ++i) {
            int r = kt * 32 + lk * 8 + i;
            bf[kt][i] = (_Float16)Wk[r * DD + ct * 16 + lr];
        }
    int nb0 = blockIdx.x * NPB;
    int node = min(nb0 + lr, N - 1);
    f32x4 d = {0.f, 0.f, 0.f, 0.f};
    #pragma unroll
    for (int kt = 0; kt < 2; ++kt)
        d = __builtin_amdgcn_mfma_f32_16x16x32_f16(afrag(P, node, kt, lk), bf[kt], d, 0, 0, 0);
    int nvb = min(NPB, N - nb0);
    int col = ct * 16 + lr;
    #pragma unroll
    for (int r = 0; r < 4; ++r) {
        int row = lk * 4 + r;
        if (row < nvb) {
            float dv = dis[nb0 + row];
            float invd = (dv > 0.f) ? 1.f / dv : 1.f;
            long long o = (long long)(nb0 + row) * DD + col;
            out[o] = out[o] + invd * d[r];
        }
    }
}

extern "C" void kernel_launch(void* const* d_in, const int* in_sizes, int n_in,
                              void* d_out, int out_size, void* d_ws, size_t ws_size,
                              hipStream_t stream) {
    const float* x  = (const float*)d_in[0];
    const int*   ei = (const int*)d_in[1];
    const float* W  = (const float*)d_in[2];
    const float* b  = (const float*)d_in[3];
    float* out = (float*)d_out;

    const int N = in_sizes[0] / DD;
    const int E = in_sizes[1] / 2;
    const int K = in_sizes[2] / (DD * DD);
    const long long ND = (long long)N * DD;
    const int NR = ((N + 3) / 4) * 4;

    const int* src = ei;
    const int* dst = ei + E;

    size_t off = 0;
    char* base = (char*)d_ws;
    auto alloc = [&](size_t bytes) {
        char* p = base + off;
        off = (off + bytes + 63) & ~(size_t)63;
        return p;
    };
    float* dis = (float*)alloc((size_t)N * 4);
    int* rowptr = (int*)alloc((size_t)(N + 1) * 4);
    int* bsum = (int*)alloc(512);
    char* hist_base = alloc((size_t)(NBD + NBS) * NR);   // dstp+srcp; dead after fill
    unsigned char* dstp = (unsigned char*)hist_base;
    unsigned char* srcp = (unsigned char*)(hist_base + (size_t)NBD * NR);
    unsigned char* ranks = (unsigned char*)alloc((size_t)E);
    int* adjS = (int*)alloc((size_t)E * 4);
    _Float16* P0 = (_Float16*)alloc((size_t)ND * 2);
    _Float16* P1 = (_Float16*)alloc((size_t)ND * 2);
    _Float16* P3 = (_Float16*)alloc((size_t)ND * 2);
    _Float16* P4 = (_Float16*)alloc((size_t)ND * 2);
    _Float16* P2 = (_Float16*)hist_base;   // overlay: hist partials dead before P2 write

    const int sliceD = (E + NBD - 1) / NBD;
    const int sliceS = (E + NBS - 1) / NBS;
    const size_t ldsH = (size_t)NR;

    histD_kernel<<<NBD, 1024, ldsH, stream>>>(dst, dstp, ranks, N, NR, E, sliceD);
    histS_kernel<<<NBS, 1024, ldsH, stream>>>(src, srcp, N, NR, E, sliceS);

    const int nb = (N + 1023) / 1024;
    scan1_kernel<<<nb, 1024, 0, stream>>>(dstp, srcp, dis, rowptr, bsum, N, NR);
    scan2_kernel<<<1, 128, 0, stream>>>(bsum, nb);
    scan3_kernel<<<(N + 255) / 256, 256, 0, stream>>>(rowptr, bsum, N, E);

    const long long n8 = ND / 8;
    cvt_kernel<<<(int)((n8 + 255) / 256), 256, 0, stream>>>(x, dis, P0, n8);

    fill_kernel<<<(E + 255) / 256, 256, 0, stream>>>(src, dst, rowptr, dstp,
                                                     ranks, adjS, E, sliceD, NR);

    const int pgrid = (N + NPB - 1) / NPB;
    const int Wsz = DD * DD;

    if (K == 5) {
        // P1 = -dis^2 * gather(P0)
        prop_kernel<<<pgrid, 256, 0, stream>>>(rowptr, adjS, dis, P0,
                                               (const _Float16*)0, P1, -1.0f, N);
        // P2 = -2 dis^2 gather(P1) - P0   (P2 overlays dead hist partials)
        prop_kernel<<<pgrid, 256, 0, stream>>>(rowptr, adjS, dis, P1, P0, P2, -2.0f, N);
        // P3 = -2 dis^2 gather(P2) - P1
        prop_kernel<<<pgrid, 256, 0, stream>>>(rowptr, adjS, dis, P2, P1, P3, -2.0f, N);
        // P4 = -2 dis^2 gather(P3) - P2
        prop_kernel<<<pgrid, 256, 0, stream>>>(rowptr, adjS, dis, P3, P2, P4, -2.0f, N);
        // out = b + invd*(P0@W0 + P1@W1 + P2@W2 + P3@W3 + P4@W4)
        gemm5_kernel<<<pgrid, 256, 0, stream>>>(P0, P1, P2, P3, P4, dis, W, b, out, N);
    } else {
        // generic: rotate 3 buffers (P0,P1,P2), accumulate per-k
        prop_kernel<<<pgrid, 256, 0, stream>>>(rowptr, adjS, dis, P0,
                                               (const _Float16*)0, P1, -1.0f, N);
        gemm2_kernel<<<pgrid, 256, 0, stream>>>(P0, P1, dis, W, W + Wsz, b, out, N);
        _Float16* t0 = P0;
        _Float16* h  = P1;
        _Float16* fr = P2;
        for (int k = 2; k < K; ++k) {
            prop_kernel<<<pgrid, 256, 0, stream>>>(rowptr, adjS, dis, h, t0, fr, -2.0f, N);
            gemm1_kernel<<<pgrid, 256, 0, stream>>>(fr, dis, W + (long long)k * Wsz,
                                                    out, N);
            _Float16* nfree = t0;
            t0 = h; h = fr; fr = nfree;
        }
    }
}